// Round 9
// baseline (840.863 us; speedup 1.0000x reference)
//
#include <hip/hip_runtime.h>
#include <stdint.h>

#define TSTEPS 1024
#define BATCH  32
#define DIMK   1024
#define HEADS  8
#define NHEAD  64
#define NPROJ  2048          // 4 * H * N
#define MROWS  (TSTEPS*BATCH)

typedef _Float16 f16;
typedef _Float16 f16x2 __attribute__((ext_vector_type(2)));
typedef _Float16 f16x4 __attribute__((ext_vector_type(4)));
typedef _Float16 f16x8 __attribute__((ext_vector_type(8)));
typedef float    f32x2 __attribute__((ext_vector_type(2)));
typedef float    f32x4 __attribute__((ext_vector_type(4)));
typedef unsigned int u32;

#define AS_GLOBAL __attribute__((address_space(1)))
#define AS_LDS    __attribute__((address_space(3)))

#define C2LOG2E 2.8853900817779268f   // 2*log2(e)

__device__ __forceinline__ void load_lds_16B(const void* g, void* l){
  __builtin_amdgcn_global_load_lds((const AS_GLOBAL u32*)g, (AS_LDS u32*)l, 16, 0, 0);
}

__device__ __forceinline__ float sigmoid_fast(float x){
  return __builtin_amdgcn_rcpf(1.0f + __expf(-x));
}

__device__ __forceinline__ float exp2_fast(float x){
#if __has_builtin(__builtin_amdgcn_exp2f)
  return __builtin_amdgcn_exp2f(x);
#else
  return __expf(0.6931471805599453f * x);
#endif
}

__device__ __forceinline__ float fdot2(f16x2 a, f16x2 b, float c){
#if __has_builtin(__builtin_amdgcn_fdot2)
  typedef __fp16 h16x2 __attribute__((ext_vector_type(2)));
  return __builtin_amdgcn_fdot2(__builtin_bit_cast(h16x2, a),
                                __builtin_bit_cast(h16x2, b), c, false);
#else
  return fmaf((float)a[1], (float)b[1], fmaf((float)a[0], (float)b[0], c));
#endif
}

__device__ __forceinline__ f16x2 pack2(float a, float b){
#if __has_builtin(__builtin_amdgcn_cvt_pkrtz)
  return __builtin_bit_cast(f16x2, __builtin_amdgcn_cvt_pkrtz(a, b));
#else
  f16x2 r = { (f16)a, (f16)b };
  return r;
#endif
}

// DPP rotate-add within 16-lane row; ROW_ROR:N ctrl = 0x120|N.
template<int CTRL>
__device__ __forceinline__ float dpp_add(float r){
  int x = __builtin_amdgcn_update_dpp(__builtin_bit_cast(int, r),
                                      __builtin_bit_cast(int, r),
                                      CTRL, 0xf, 0xf, false);
  return r + __builtin_bit_cast(float, x);
}
__device__ __forceinline__ float dpp_reduce16(float r){
  r = dpp_add<0x121>(r);
  r = dpp_add<0x122>(r);
  r = dpp_add<0x124>(r);
  r = dpp_add<0x128>(r);
  return r;
}

// ---------------- cast f32 -> f16 (vectorized) ----------------
__global__ __launch_bounds__(256) void cast_kernel(const float4* __restrict__ src,
                                                   f16x4* __restrict__ dst, int n4){
  int i = blockIdx.x*blockDim.x + threadIdx.x;
  int stride = gridDim.x*blockDim.x;
  for (; i < n4; i += stride){
    float4 v = src[i];
    f16x4 o = { (f16)v.x, (f16)v.y, (f16)v.z, (f16)v.w };
    dst[i] = o;
  }
}

// ---------------- GEMM: writes scan-layout Z ----------------
// Z[pair=b*8+h][t][256 f16]: k[e]@e, q[e]@64+e, v[e]@128+2e, braw[e]@129+2e
#define BM 128
#define BN 128
#define BK 32

__global__ __launch_bounds__(256) void gemm_xwT(const f16* __restrict__ A,  // MROWS x DIMK
                                                const f16* __restrict__ B,  // NPROJ x DIMK
                                                f16* __restrict__ Zo){
  __shared__ f16 sA[BM*BK];
  __shared__ f16 sB[BN*BK];
  const int t = threadIdx.x;
  const int w = t >> 6;
  const int l = t & 63;
  const int bm = blockIdx.x;
  const int bn = blockIdx.y;
  const int wr = w >> 1, wc = w & 1;

  f32x4 acc[4][4] = {};

  const int srow = t >> 2;
  const int scol = (t & 3) * 8;
  const f16* gA0 = A + (size_t)(bm*BM + srow)*DIMK + scol;
  const f16* gB0 = B + (size_t)(bn*BN + srow)*DIMK + scol;
  char* sAb = (char*)sA;
  char* sBb = (char*)sB;
  const int ldsw = w*1024;

  for (int kk = 0; kk < DIMK/BK; ++kk){
    const f16* pa = gA0 + kk*BK;
    const f16* pb = gB0 + kk*BK;
    load_lds_16B(pa,           sAb + ldsw);
    load_lds_16B(pa + 64*DIMK, sAb + ldsw + 4096);
    load_lds_16B(pb,           sBb + ldsw);
    load_lds_16B(pb + 64*DIMK, sBb + ldsw + 4096);
    __syncthreads();

    f16x8 af[4], bf[4];
    #pragma unroll
    for (int mi=0; mi<4; ++mi){
      int arow = wr*64 + mi*16 + (l & 15);
      af[mi] = *(const f16x8*)(sAb + arow*64 + (l>>4)*16);
    }
    #pragma unroll
    for (int ni=0; ni<4; ++ni){
      int brow = wc*64 + ni*16 + (l & 15);
      bf[ni] = *(const f16x8*)(sBb + brow*64 + (l>>4)*16);
    }
    #pragma unroll
    for (int mi=0; mi<4; ++mi)
      #pragma unroll
      for (int ni=0; ni<4; ++ni)
        acc[mi][ni] = __builtin_amdgcn_mfma_f32_16x16x32_f16(af[mi], bf[ni], acc[mi][ni], 0, 0, 0);
    __syncthreads();
  }

  // scatter into Z layout. stream: 0=k,1=v,2=q,3=braw (W stack order k|v|q|beta)
  const int crow0 = bm*BM + wr*64 + (l>>4)*4;
  const int ccol0 = bn*BN + wc*64 + (l & 15);
  #pragma unroll
  for (int ni=0; ni<4; ++ni){
    int n = ccol0 + ni*16;
    int stream = n >> 9;
    int hh = (n >> 6) & 7;
    int e = n & 63;
    int eidx = (stream==0) ? e : (stream==2) ? 64+e : (stream==1) ? 128+2*e : 129+2*e;
    #pragma unroll
    for (int mi=0; mi<4; ++mi)
      #pragma unroll
      for (int r=0; r<4; ++r){
        int m = crow0 + mi*16 + r;
        int ti = m >> 5, bi = m & 31;
        size_t zi = ((size_t)(bi*8 + hh)*1024 + ti)*256 + eidx;
        Zo[zi] = (f16)acc[mi][ni][r];
      }
  }
}

// ---------------- prep (in place over Z): kn = k/(||k||+eps), bs = C2LOG2E*sigmoid ----
__global__ __launch_bounds__(256) void prep_kernel(f16* __restrict__ Z,
                                                   const float* __restrict__ b_beta){
  int wid = blockIdx.x*4 + (threadIdx.x >> 6);   // [0, 256*1024) = (pair,t)
  int l = threadIdx.x & 63;
  int h = (wid >> 10) & 7;
  f16* z = Z + (size_t)wid * 256;
  float k  = (float)z[l];
  float br = (float)z[129 + 2*l];
  float ss = k*k;
  #pragma unroll
  for (int d=1; d<64; d<<=1) ss += __shfl_xor(ss, d);
  z[l]       = (f16)(k * __builtin_amdgcn_rcpf(__builtin_sqrtf(ss) + 1e-6f));
  z[129+2*l] = (f16)(C2LOG2E * sigmoid_fast(br + b_beta[h*NHEAD + l]));
}

// ---------------- recurrent scan: LDS-staged, DPP reductions ----------------
// thread t: row=t>>4, g=t&15 owns cols [g*4,g*4+4). 16 waves/pair.
// 64-step stages staged global->LDS via global_load_lds, double-buffered.
#define STAGE_STEPS 64
#define STAGE_F16   (STAGE_STEPS*256)   // 16384 f16 = 32 KB

__global__ __launch_bounds__(1024) void scan_kernel(const f16* __restrict__ Z,
                                                    float* __restrict__ out,
                                                    float* __restrict__ S_out){
  const int p = blockIdx.x;          // pair 0..255
  const int b = p >> 3, h = p & 7;
  const int t = threadIdx.x;         // 0..1023
  const int w = t >> 6;
  const int lane = t & 63;
  const int row = t >> 4;
  const int g   = t & 15;

  __shared__ f16 lds[2*STAGE_F16];   // 64 KB

  f32x2 S01 = {0.f,0.f}, S23 = {0.f,0.f};
  f16x2 P0 = {}, P1 = {};

  const char* Zp = (const char*)(Z + (size_t)p * (TSTEPS*256));
  float* outp = out + (size_t)b*512 + h*NHEAD + row;
  char* ldsb = (char*)lds;

  // prologue: stage 0
  {
    const char* src = Zp + w*2048 + lane*16;
    load_lds_16B(src,        ldsb + w*2048);
    load_lds_16B(src + 1024, ldsb + w*2048 + 1024);
  }
  __syncthreads();

  #pragma unroll 1
  for (int st=0; st<TSTEPS/STAGE_STEPS; ++st){
    // prefetch next stage into other buffer
    if (st < TSTEPS/STAGE_STEPS - 1){
      const char* src = Zp + (st+1)*(STAGE_F16*2) + w*2048 + lane*16;
      char* dst = ldsb + ((st+1)&1)*(STAGE_F16*2) + w*2048;
      load_lds_16B(src,        dst);
      load_lds_16B(src + 1024, dst + 1024);
    }

    const f16* buf = lds + (st&1)*STAGE_F16;
    #pragma unroll 4
    for (int s=0; s<STAGE_STEPS; ++s){
      const f16* ps = buf + s*256;
      f16x4 k4 = *(const f16x4*)(ps + g*4);
      f16x4 q4 = *(const f16x4*)(ps + 64 + g*4);
      f16x2 vb = *(const f16x2*)(ps + 128 + row*2);

      uint2 ku = __builtin_bit_cast(uint2, k4);
      uint2 qu = __builtin_bit_cast(uint2, q4);
      f16x2 kl = __builtin_bit_cast(f16x2, ku.x), kh = __builtin_bit_cast(f16x2, ku.y);
      f16x2 ql = __builtin_bit_cast(f16x2, qu.x), qh = __builtin_bit_cast(f16x2, qu.y);
      float v  = (float)vb[0];
      float bb = (float)vb[1];

      float r = fdot2(P1, kh, fdot2(P0, kl, 0.f));
      r = dpp_reduce16(r);
      float dl = (v - r) * C2LOG2E;

      f32x2 d2  = { dl, dl };
      f32x2 bb2 = { bb, bb };
      f32x2 k01 = { (float)kl[0], (float)kl[1] };
      f32x2 k23 = { (float)kh[0], (float)kh[1] };
      f32x2 arg01 = bb2*S01 + d2*k01;     // v_pk_fma_f32
      f32x2 arg23 = bb2*S23 + d2*k23;

      f32x2 e01 = { exp2_fast(arg01.x), exp2_fast(arg01.y) };
      f32x2 e23 = { exp2_fast(arg23.x), exp2_fast(arg23.y) };
      f32x2 one2 = { 1.f, 1.f };
      e01 += one2;  e23 += one2;
      f32x2 t01 = { __builtin_amdgcn_rcpf(e01.x), __builtin_amdgcn_rcpf(e01.y) };
      f32x2 t23 = { __builtin_amdgcn_rcpf(e23.x), __builtin_amdgcn_rcpf(e23.y) };
      f32x2 m2 = { -2.f, -2.f };
      S01 = m2*t01 + one2;
      S23 = m2*t23 + one2;
      P0 = pack2(S01.x, S01.y);
      P1 = pack2(S23.x, S23.y);

      float sq = fdot2(P1, qh, fdot2(P0, ql, 0.f));
      sq = dpp_reduce16(sq);
      if (g == 0) outp[(size_t)(st*STAGE_STEPS + s) * (BATCH*512)] = sq;
    }
    __syncthreads();
  }

  // S_final: [B, H, n, n]
  size_t sbase = ((size_t)p*NHEAD + row)*NHEAD + g*4;
  float4 v4 = { S01.x, S01.y, S23.x, S23.y };
  *(float4*)(S_out + sbase) = v4;
}

// ---------------- postpass: out = sq * silu(sq), in place ----------------
__global__ __launch_bounds__(256) void silu_kernel(float4* __restrict__ o, int n4){
  int i = blockIdx.x*blockDim.x + threadIdx.x;
  int stride = gridDim.x*blockDim.x;
  for (; i < n4; i += stride){
    float4 v = o[i];
    v.x = v.x*v.x*sigmoid_fast(v.x);
    v.y = v.y*v.y*sigmoid_fast(v.y);
    v.z = v.z*v.z*sigmoid_fast(v.z);
    v.w = v.w*v.w*sigmoid_fast(v.w);
    o[i] = v;
  }
}

// ---------------- launch ----------------
extern "C" void kernel_launch(void* const* d_in, const int* in_sizes, int n_in,
                              void* d_out, int out_size, void* d_ws, size_t ws_size,
                              hipStream_t stream){
  const float* x  = (const float*)d_in[0];
  const float* Wk = (const float*)d_in[1];
  const float* Wv = (const float*)d_in[2];
  const float* Wq = (const float*)d_in[3];
  const float* Wb = (const float*)d_in[4];
  const float* bb = (const float*)d_in[5];

  float* out = (float*)d_out;
  float* Sf  = out + (size_t)TSTEPS*BATCH*512;

  char* ws = (char*)d_ws;
  f16* Zh = (f16*)ws;                                // 128 MB (scan layout)
  f16* xh = (f16*)(ws + 134217728);                  // 64 MB
  f16* wh = (f16*)(ws + 134217728 + 67108864);       // 4 MB

  cast_kernel<<<2048, 256, 0, stream>>>((const float4*)x,  (f16x4*)xh, (MROWS*DIMK)/4);
  cast_kernel<<<512,  256, 0, stream>>>((const float4*)Wk, (f16x4*)(wh + 0*524288), 524288/4);
  cast_kernel<<<512,  256, 0, stream>>>((const float4*)Wv, (f16x4*)(wh + 1*524288), 524288/4);
  cast_kernel<<<512,  256, 0, stream>>>((const float4*)Wq, (f16x4*)(wh + 2*524288), 524288/4);
  cast_kernel<<<512,  256, 0, stream>>>((const float4*)Wb, (f16x4*)(wh + 3*524288), 524288/4);

  dim3 g(MROWS/BM, NPROJ/BN);
  gemm_xwT<<<g, 256, 0, stream>>>(xh, wh, Zh);

  prep_kernel<<<(TSTEPS*BATCH*HEADS)/4, 256, 0, stream>>>(Zh, bb);

  scan_kernel<<<256, 1024, 0, stream>>>(Zh, out, Sf);

  silu_kernel<<<2048, 256, 0, stream>>>((float4*)out, (TSTEPS*BATCH*512)/4);
}

// Round 10
// 763.674 us; speedup vs baseline: 1.1011x; 1.1011x over previous
//
#include <hip/hip_runtime.h>
#include <stdint.h>

#define TSTEPS 1024
#define BATCH  32
#define DIMK   1024
#define HEADS  8
#define NHEAD  64
#define NPROJ  2048          // 4 * H * N
#define MROWS  (TSTEPS*BATCH)

typedef _Float16 f16;
typedef _Float16 f16x2 __attribute__((ext_vector_type(2)));
typedef _Float16 f16x4 __attribute__((ext_vector_type(4)));
typedef _Float16 f16x8 __attribute__((ext_vector_type(8)));
typedef float    f32x2 __attribute__((ext_vector_type(2)));
typedef float    f32x4 __attribute__((ext_vector_type(4)));
typedef unsigned int u32;

#define AS_GLOBAL __attribute__((address_space(1)))
#define AS_LDS    __attribute__((address_space(3)))

#define C2LOG2E 2.8853900817779268f   // 2*log2(e)

__device__ __forceinline__ void load_lds_16B(const void* g, void* l){
  __builtin_amdgcn_global_load_lds((const AS_GLOBAL u32*)g, (AS_LDS u32*)l, 16, 0, 0);
}

__device__ __forceinline__ float sigmoid_fast(float x){
  return __builtin_amdgcn_rcpf(1.0f + __expf(-x));
}

__device__ __forceinline__ float exp2_fast(float x){
#if __has_builtin(__builtin_amdgcn_exp2f)
  return __builtin_amdgcn_exp2f(x);
#else
  return __expf(0.6931471805599453f * x);
#endif
}

__device__ __forceinline__ float fdot2(f16x2 a, f16x2 b, float c){
#if __has_builtin(__builtin_amdgcn_fdot2)
  typedef __fp16 h16x2 __attribute__((ext_vector_type(2)));
  return __builtin_amdgcn_fdot2(__builtin_bit_cast(h16x2, a),
                                __builtin_bit_cast(h16x2, b), c, false);
#else
  return fmaf((float)a[1], (float)b[1], fmaf((float)a[0], (float)b[0], c));
#endif
}

__device__ __forceinline__ f16x2 pack2(float a, float b){
#if __has_builtin(__builtin_amdgcn_cvt_pkrtz)
  return __builtin_bit_cast(f16x2, __builtin_amdgcn_cvt_pkrtz(a, b));
#else
  f16x2 r = { (f16)a, (f16)b };
  return r;
#endif
}

// DPP rotate-add within 16-lane row; ROW_ROR:N ctrl = 0x120|N.
template<int CTRL>
__device__ __forceinline__ float dpp_add(float r){
  int x = __builtin_amdgcn_update_dpp(__builtin_bit_cast(int, r),
                                      __builtin_bit_cast(int, r),
                                      CTRL, 0xf, 0xf, false);
  return r + __builtin_bit_cast(float, x);
}
__device__ __forceinline__ float dpp_reduce16(float r){
  r = dpp_add<0x121>(r);
  r = dpp_add<0x122>(r);
  r = dpp_add<0x124>(r);
  r = dpp_add<0x128>(r);
  return r;
}

// ---------------- cast f32 -> f16 (vectorized) ----------------
__global__ __launch_bounds__(256) void cast_kernel(const float4* __restrict__ src,
                                                   f16x4* __restrict__ dst, int n4){
  int i = blockIdx.x*blockDim.x + threadIdx.x;
  int stride = gridDim.x*blockDim.x;
  for (; i < n4; i += stride){
    float4 v = src[i];
    f16x4 o = { (f16)v.x, (f16)v.y, (f16)v.z, (f16)v.w };
    dst[i] = o;
  }
}

// ---------------- GEMM: Y[m][n] = sum_k X[m][k] * W[n][k] (row-major Y) ----------------
#define BM 128
#define BN 128
#define BK 32

__global__ __launch_bounds__(256) void gemm_xwT(const f16* __restrict__ A,  // MROWS x DIMK
                                                const f16* __restrict__ B,  // NPROJ x DIMK
                                                f16* __restrict__ C){       // MROWS x NPROJ
  __shared__ f16 sA[BM*BK];
  __shared__ f16 sB[BN*BK];
  const int t = threadIdx.x;
  const int w = t >> 6;
  const int l = t & 63;
  const int bm = blockIdx.x;
  const int bn = blockIdx.y;
  const int wr = w >> 1, wc = w & 1;

  f32x4 acc[4][4] = {};

  const int srow = t >> 2;
  const int scol = (t & 3) * 8;
  const f16* gA0 = A + (size_t)(bm*BM + srow)*DIMK + scol;
  const f16* gB0 = B + (size_t)(bn*BN + srow)*DIMK + scol;
  char* sAb = (char*)sA;
  char* sBb = (char*)sB;
  const int ldsw = w*1024;

  for (int kk = 0; kk < DIMK/BK; ++kk){
    const f16* pa = gA0 + kk*BK;
    const f16* pb = gB0 + kk*BK;
    load_lds_16B(pa,           sAb + ldsw);
    load_lds_16B(pa + 64*DIMK, sAb + ldsw + 4096);
    load_lds_16B(pb,           sBb + ldsw);
    load_lds_16B(pb + 64*DIMK, sBb + ldsw + 4096);
    __syncthreads();

    f16x8 af[4], bf[4];
    #pragma unroll
    for (int mi=0; mi<4; ++mi){
      int arow = wr*64 + mi*16 + (l & 15);
      af[mi] = *(const f16x8*)(sAb + arow*64 + (l>>4)*16);
    }
    #pragma unroll
    for (int ni=0; ni<4; ++ni){
      int brow = wc*64 + ni*16 + (l & 15);
      bf[ni] = *(const f16x8*)(sBb + brow*64 + (l>>4)*16);
    }
    #pragma unroll
    for (int mi=0; mi<4; ++mi)
      #pragma unroll
      for (int ni=0; ni<4; ++ni)
        acc[mi][ni] = __builtin_amdgcn_mfma_f32_16x16x32_f16(af[mi], bf[ni], acc[mi][ni], 0, 0, 0);
    __syncthreads();
  }

  const int crow0 = bm*BM + wr*64 + (l>>4)*4;
  const int ccol0 = bn*BN + wc*64 + (l & 15);
  #pragma unroll
  for (int mi=0; mi<4; ++mi)
    #pragma unroll
    for (int ni=0; ni<4; ++ni)
      #pragma unroll
      for (int r=0; r<4; ++r)
        C[(size_t)(crow0 + mi*16 + r)*NPROJ + ccol0 + ni*16] = (f16)acc[mi][ni][r];
}

// ---------------- prep: in-place kn = k/(||k||+eps), bs = C2LOG2E*sigmoid(braw+bias) ----
__global__ __launch_bounds__(256) void prep_kernel(f16* __restrict__ Y,
                                                   const float* __restrict__ b_beta){
  int g = blockIdx.x*4 + (threadIdx.x >> 6);   // [0, T*B*H)
  int l = threadIdx.x & 63;
  int h = g & 7;
  f16* y = Y + (size_t)(g >> 3)*NPROJ + h*NHEAD + l;
  float k  = (float)y[0];
  float br = (float)y[1536];
  float ss = k*k;
  #pragma unroll
  for (int d=1; d<64; d<<=1) ss += __shfl_xor(ss, d);
  y[0]    = (f16)(k * __builtin_amdgcn_rcpf(__builtin_sqrtf(ss) + 1e-6f));
  y[1536] = (f16)(C2LOG2E * sigmoid_fast(br + b_beta[h*NHEAD + l]));
}

// ---------------- recurrent scan: transpose-on-stage LDS, DPP reductions ----------------
// thread t: row = t>>4, g = t&15 owns cols [g*4,g*4+4). 16 waves/pair.
// Staging: per-lane Y-layout source -> linear LDS in step-major k|v|q|beta order.
// LDS per step: 512B = k[64]|v[64]|q[64]|beta[64] f16.
#define STAGE_STEPS 64
#define STAGE_F16   (STAGE_STEPS*256)   // 16384 f16 = 32 KB per buffer
#define STAGE_BYTES 32768
#define NSTAGES     (TSTEPS/STAGE_STEPS)

__global__ __launch_bounds__(1024) void scan_kernel(const f16* __restrict__ Y,
                                                    float* __restrict__ out,
                                                    float* __restrict__ S_out){
  const int p = blockIdx.x;          // pair 0..255
  const int b = p >> 3, h = p & 7;
  const int t = threadIdx.x;         // 0..1023
  const int w = t >> 6;
  const int row = t >> 4;
  const int g   = t & 15;

  __shared__ f16 lds[2*STAGE_F16];   // 64 KB

  f32x2 S01 = {0.f,0.f}, S23 = {0.f,0.f};
  f16x2 P0 = {}, P1 = {};

  float* outp = out + (size_t)b*512 + h*NHEAD + row;
  char* ldsb = (char*)lds;

  // per-thread global source for 16B chunk c (c = t and t+1024):
  // t_local = c>>5, r = c&31, stream = r>>3, e8 = r&7
  // Y addr = ((t_local*32 + b) * NPROJ + stream*512 + h*64 + e8*8) f16
  auto mksrc = [&](int c) -> const char* {
    int tl = c >> 5, rr = c & 31, stream = rr >> 3, e8 = rr & 7;
    return (const char*)(Y + ((size_t)tl*BATCH + b)*NPROJ + stream*512 + h*NHEAD + e8*8);
  };
  const char* src0 = mksrc(t);
  const char* src1 = mksrc(t + 1024);
  const size_t SADV = (size_t)STAGE_STEPS*BATCH*NPROJ*sizeof(f16);   // 8 MB

  char* d0 = ldsb + w*1024;
  char* d1 = ldsb + 16384 + w*1024;

  // prologue: stage 0
  load_lds_16B(src0, d0);
  load_lds_16B(src1, d1);
  src0 += SADV; src1 += SADV;
  __syncthreads();

  #pragma unroll 1
  for (int st=0; st<NSTAGES; ++st){
    if (st < NSTAGES-1){
      char* dst = ldsb + ((st+1)&1)*STAGE_BYTES;
      load_lds_16B(src0, dst + w*1024);
      load_lds_16B(src1, dst + 16384 + w*1024);
      src0 += SADV; src1 += SADV;
    }

    const char* buf = ldsb + (st&1)*STAGE_BYTES;
    #pragma unroll 4
    for (int s=0; s<STAGE_STEPS; ++s){
      const char* psb = buf + s*512;
      f16x4 k4 = *(const f16x4*)(psb + g*8);
      f16x4 q4 = *(const f16x4*)(psb + 256 + g*8);
      f16 vh   = *(const f16*)(psb + 128 + row*2);
      f16 bh   = *(const f16*)(psb + 384 + row*2);

      uint2 ku = __builtin_bit_cast(uint2, k4);
      uint2 qu = __builtin_bit_cast(uint2, q4);
      f16x2 kl = __builtin_bit_cast(f16x2, ku.x), kh = __builtin_bit_cast(f16x2, ku.y);
      f16x2 ql = __builtin_bit_cast(f16x2, qu.x), qh = __builtin_bit_cast(f16x2, qu.y);
      float v  = (float)vh;
      float bb = (float)bh;   // pre-scaled by C2LOG2E

      float r = fdot2(P1, kh, fdot2(P0, kl, 0.f));
      r = dpp_reduce16(r);
      float dl = (v - r) * C2LOG2E;

      f32x2 d2  = { dl, dl };
      f32x2 bb2 = { bb, bb };
      f32x2 k01 = { (float)kl[0], (float)kl[1] };
      f32x2 k23 = { (float)kh[0], (float)kh[1] };
      f32x2 arg01 = bb2*S01 + d2*k01;     // v_pk_fma_f32
      f32x2 arg23 = bb2*S23 + d2*k23;

      f32x2 e01 = { exp2_fast(arg01.x), exp2_fast(arg01.y) };
      f32x2 e23 = { exp2_fast(arg23.x), exp2_fast(arg23.y) };
      f32x2 one2 = { 1.f, 1.f };
      e01 += one2;  e23 += one2;
      f32x2 t01 = { __builtin_amdgcn_rcpf(e01.x), __builtin_amdgcn_rcpf(e01.y) };
      f32x2 t23 = { __builtin_amdgcn_rcpf(e23.x), __builtin_amdgcn_rcpf(e23.y) };
      f32x2 m2 = { -2.f, -2.f };
      S01 = m2*t01 + one2;
      S23 = m2*t23 + one2;
      P0 = pack2(S01.x, S01.y);
      P1 = pack2(S23.x, S23.y);

      float sq = fdot2(P1, qh, fdot2(P0, ql, 0.f));
      sq = dpp_reduce16(sq);
      if (g == 0) outp[(size_t)(st*STAGE_STEPS + s) * (BATCH*512)] = sq;
    }
    __syncthreads();
  }

  // S_final: [B, H, n, n]
  size_t sbase = ((size_t)p*NHEAD + row)*NHEAD + g*4;
  float4 v4 = { S01.x, S01.y, S23.x, S23.y };
  *(float4*)(S_out + sbase) = v4;
}

// ---------------- postpass: out = sq * silu(sq), in place ----------------
__global__ __launch_bounds__(256) void silu_kernel(float4* __restrict__ o, int n4){
  int i = blockIdx.x*blockDim.x + threadIdx.x;
  int stride = gridDim.x*blockDim.x;
  for (; i < n4; i += stride){
    float4 v = o[i];
    v.x = v.x*v.x*sigmoid_fast(v.x);
    v.y = v.y*v.y*sigmoid_fast(v.y);
    v.z = v.z*v.z*sigmoid_fast(v.z);
    v.w = v.w*v.w*sigmoid_fast(v.w);
    o[i] = v;
  }
}

// ---------------- launch ----------------
extern "C" void kernel_launch(void* const* d_in, const int* in_sizes, int n_in,
                              void* d_out, int out_size, void* d_ws, size_t ws_size,
                              hipStream_t stream){
  const float* x  = (const float*)d_in[0];
  const float* Wk = (const float*)d_in[1];
  const float* Wv = (const float*)d_in[2];
  const float* Wq = (const float*)d_in[3];
  const float* Wb = (const float*)d_in[4];
  const float* bb = (const float*)d_in[5];

  float* out = (float*)d_out;
  float* Sf  = out + (size_t)TSTEPS*BATCH*512;

  char* ws = (char*)d_ws;
  f16* Yh = (f16*)ws;                                // 128 MB (row-major T*B x 2048)
  f16* xh = (f16*)(ws + 134217728);                  // 64 MB
  f16* wh = (f16*)(ws + 134217728 + 67108864);       // 4 MB

  cast_kernel<<<2048, 256, 0, stream>>>((const float4*)x,  (f16x4*)xh, (MROWS*DIMK)/4);
  cast_kernel<<<512,  256, 0, stream>>>((const float4*)Wk, (f16x4*)(wh + 0*524288), 524288/4);
  cast_kernel<<<512,  256, 0, stream>>>((const float4*)Wv, (f16x4*)(wh + 1*524288), 524288/4);
  cast_kernel<<<512,  256, 0, stream>>>((const float4*)Wq, (f16x4*)(wh + 2*524288), 524288/4);
  cast_kernel<<<512,  256, 0, stream>>>((const float4*)Wb, (f16x4*)(wh + 3*524288), 524288/4);

  dim3 g(MROWS/BM, NPROJ/BN);
  gemm_xwT<<<g, 256, 0, stream>>>(xh, wh, Yh);

  prep_kernel<<<(TSTEPS*BATCH*HEADS)/4, 256, 0, stream>>>(Yh, bb);

  scan_kernel<<<256, 1024, 0, stream>>>(Yh, out, Sf);

  silu_kernel<<<2048, 256, 0, stream>>>((float4*)out, (TSTEPS*BATCH*512)/4);
}

// Round 16
// 758.897 us; speedup vs baseline: 1.1080x; 1.0063x over previous
//
#include <hip/hip_runtime.h>
#include <stdint.h>

#define TSTEPS 1024
#define BATCH  32
#define DIMK   1024
#define HEADS  8
#define NHEAD  64
#define NPROJ  2048          // 4 * H * N
#define MROWS  (TSTEPS*BATCH)

typedef _Float16 f16;
typedef _Float16 f16x2 __attribute__((ext_vector_type(2)));
typedef _Float16 f16x4 __attribute__((ext_vector_type(4)));
typedef _Float16 f16x8 __attribute__((ext_vector_type(8)));
typedef float    f32x2 __attribute__((ext_vector_type(2)));
typedef float    f32x4 __attribute__((ext_vector_type(4)));
typedef unsigned int u32;
typedef unsigned short u16;

#define AS_GLOBAL __attribute__((address_space(1)))
#define AS_LDS    __attribute__((address_space(3)))

#define C2LOG2E 2.8853900817779268f   // 2*log2(e)

__device__ __forceinline__ void load_lds_16B(const void* g, void* l){
  __builtin_amdgcn_global_load_lds((const AS_GLOBAL u32*)g, (AS_LDS u32*)l, 16, 0, 0);
}

__device__ __forceinline__ float sigmoid_fast(float x){
  return __builtin_amdgcn_rcpf(1.0f + __expf(-x));
}

__device__ __forceinline__ float exp2_fast(float x){
#if __has_builtin(__builtin_amdgcn_exp2f)
  return __builtin_amdgcn_exp2f(x);
#else
  return __expf(0.6931471805599453f * x);
#endif
}

__device__ __forceinline__ float fdot2(f16x2 a, f16x2 b, float c){
#if __has_builtin(__builtin_amdgcn_fdot2)
  typedef __fp16 h16x2 __attribute__((ext_vector_type(2)));
  return __builtin_amdgcn_fdot2(__builtin_bit_cast(h16x2, a),
                                __builtin_bit_cast(h16x2, b), c, false);
#else
  return fmaf((float)a[1], (float)b[1], fmaf((float)a[0], (float)b[0], c));
#endif
}

__device__ __forceinline__ f16x2 pack2(float a, float b){
#if __has_builtin(__builtin_amdgcn_cvt_pkrtz)
  return __builtin_bit_cast(f16x2, __builtin_amdgcn_cvt_pkrtz(a, b));
#else
  f16x2 r = { (f16)a, (f16)b };
  return r;
#endif
}

// DPP rotate-add within 16-lane rows via builtin (PROVEN correct R8-R10; the
// inline-asm v_add_f32_dpp form was silently wrong R13-R15 — do not resurrect).
template<int CTRL>
__device__ __forceinline__ float dpp_add(float r){
  int x = __builtin_amdgcn_update_dpp(__builtin_bit_cast(int, r),
                                      __builtin_bit_cast(int, r),
                                      CTRL, 0xf, 0xf, false);
  return r + __builtin_bit_cast(float, x);
}
__device__ __forceinline__ float dpp_reduce16(float r){
  r = dpp_add<0x121>(r);
  r = dpp_add<0x122>(r);
  r = dpp_add<0x124>(r);
  r = dpp_add<0x128>(r);
  return r;
}

// ---------------- casts f32 -> f16 (vectorized) ----------------
__global__ __launch_bounds__(256) void cast_kernel(const float4* __restrict__ src,
                                                   f16x4* __restrict__ dst, int n4){
  int i = blockIdx.x*blockDim.x + threadIdx.x;
  int stride = gridDim.x*blockDim.x;
  for (; i < n4; i += stride){
    float4 v = src[i];
    f16x4 o = { (f16)v.x, (f16)v.y, (f16)v.z, (f16)v.w };
    dst[i] = o;
  }
}

// all four W matrices in one launch; each is 524288 f32 = 131072 float4 (2^17)
__global__ __launch_bounds__(256) void cast4_kernel(const float4* __restrict__ s0,
                                                    const float4* __restrict__ s1,
                                                    const float4* __restrict__ s2,
                                                    const float4* __restrict__ s3,
                                                    f16x4* __restrict__ dst){
  int i = blockIdx.x*blockDim.x + threadIdx.x;   // [0, 4*131072)
  int seg = i >> 17, j = i & 131071;
  const float4* s = (seg==0) ? s0 : (seg==1) ? s1 : (seg==2) ? s2 : s3;
  float4 v = s[j];
  f16x4 o = { (f16)v.x, (f16)v.y, (f16)v.z, (f16)v.w };
  dst[i] = o;
}

// ---------------- GEMM: Y[m][n] = sum_k X[m][k] * W[n][k] (row-major Y) ----------------
#define BM 128
#define BN 128
#define BK 32

__global__ __launch_bounds__(256) void gemm_xwT(const f16* __restrict__ A,  // MROWS x DIMK
                                                const f16* __restrict__ B,  // NPROJ x DIMK
                                                f16* __restrict__ C){       // MROWS x NPROJ
  __shared__ f16 sA[BM*BK];
  __shared__ f16 sB[BN*BK];
  const int t = threadIdx.x;
  const int w = t >> 6;
  const int l = t & 63;
  const int bm = blockIdx.x;
  const int bn = blockIdx.y;
  const int wr = w >> 1, wc = w & 1;

  f32x4 acc[4][4] = {};

  const int srow = t >> 2;
  const int scol = (t & 3) * 8;
  const f16* gA0 = A + (size_t)(bm*BM + srow)*DIMK + scol;
  const f16* gB0 = B + (size_t)(bn*BN + srow)*DIMK + scol;
  char* sAb = (char*)sA;
  char* sBb = (char*)sB;
  const int ldsw = w*1024;

  for (int kk = 0; kk < DIMK/BK; ++kk){
    const f16* pa = gA0 + kk*BK;
    const f16* pb = gB0 + kk*BK;
    load_lds_16B(pa,           sAb + ldsw);
    load_lds_16B(pa + 64*DIMK, sAb + ldsw + 4096);
    load_lds_16B(pb,           sBb + ldsw);
    load_lds_16B(pb + 64*DIMK, sBb + ldsw + 4096);
    __syncthreads();

    f16x8 af[4], bf[4];
    #pragma unroll
    for (int mi=0; mi<4; ++mi){
      int arow = wr*64 + mi*16 + (l & 15);
      af[mi] = *(const f16x8*)(sAb + arow*64 + (l>>4)*16);
    }
    #pragma unroll
    for (int ni=0; ni<4; ++ni){
      int brow = wc*64 + ni*16 + (l & 15);
      bf[ni] = *(const f16x8*)(sBb + brow*64 + (l>>4)*16);
    }
    #pragma unroll
    for (int mi=0; mi<4; ++mi)
      #pragma unroll
      for (int ni=0; ni<4; ++ni)
        acc[mi][ni] = __builtin_amdgcn_mfma_f32_16x16x32_f16(af[mi], bf[ni], acc[mi][ni], 0, 0, 0);
    __syncthreads();
  }

  const int crow0 = bm*BM + wr*64 + (l>>4)*4;
  const int ccol0 = bn*BN + wc*64 + (l & 15);
  #pragma unroll
  for (int mi=0; mi<4; ++mi)
    #pragma unroll
    for (int ni=0; ni<4; ++ni)
      #pragma unroll
      for (int r=0; r<4; ++r)
        C[(size_t)(crow0 + mi*16 + r)*NPROJ + ccol0 + ni*16] = (f16)acc[mi][ni][r];
}

// ---------------- prep: in-place kn = k/(||k||+eps), bs = C2LOG2E*sigmoid(braw+bias) ----
__global__ __launch_bounds__(256) void prep_kernel(f16* __restrict__ Y,
                                                   const float* __restrict__ b_beta){
  int g = blockIdx.x*4 + (threadIdx.x >> 6);   // [0, T*B*H)
  int l = threadIdx.x & 63;
  int h = g & 7;
  f16* y = Y + (size_t)(g >> 3)*NPROJ + h*NHEAD + l;
  float k  = (float)y[0];
  float br = (float)y[1536];
  float ss = k*k;
  #pragma unroll
  for (int d=1; d<64; d<<=1) ss += __shfl_xor(ss, d);
  y[0]    = (f16)(k * __builtin_amdgcn_rcpf(__builtin_sqrtf(ss) + 1e-6f));
  y[1536] = (f16)(C2LOG2E * sigmoid_fast(br + b_beta[h*NHEAD + l]));
}

// ---------------- recurrent scan: f32 recurrence, transpose-on-stage LDS (R10 verbatim) ----
// thread t: row = t>>4, g = t&15 owns cols [g*4,g*4+4). 16 waves/pair.
// LDS per step: 512B = k[64]|v[64]|q[64]|beta[64] f16 (Y stream order k,v,q,beta).
#define STAGE_STEPS 64
#define STAGE_F16   (STAGE_STEPS*256)   // 32 KB per buffer
#define STAGE_BYTES 32768
#define NSTAGES     (TSTEPS/STAGE_STEPS)

__global__ __launch_bounds__(1024) void scan_kernel(const f16* __restrict__ Y,
                                                    float* __restrict__ out,
                                                    float* __restrict__ S_out){
  const int p = blockIdx.x;          // pair 0..255
  const int b = p >> 3, h = p & 7;
  const int t = threadIdx.x;         // 0..1023
  const int w = t >> 6;
  const int row = t >> 4;
  const int g   = t & 15;

  __shared__ f16 lds[2*STAGE_F16];   // 64 KB

  f32x2 S01 = {0.f,0.f}, S23 = {0.f,0.f};
  f16x2 P0 = {}, P1 = {};

  float* outp = out + (size_t)b*512 + h*NHEAD + row;
  char* ldsb = (char*)lds;

  auto mksrc = [&](int c) -> const char* {
    int tl = c >> 5, rr = c & 31, stream = rr >> 3, e8 = rr & 7;
    return (const char*)(Y + ((size_t)tl*BATCH + b)*NPROJ + stream*512 + h*NHEAD + e8*8);
  };
  const char* src0 = mksrc(t);
  const char* src1 = mksrc(t + 1024);
  const size_t SADV = (size_t)STAGE_STEPS*BATCH*NPROJ*sizeof(f16);   // 8 MB

  load_lds_16B(src0, ldsb + w*1024);
  load_lds_16B(src1, ldsb + 16384 + w*1024);
  src0 += SADV; src1 += SADV;
  __syncthreads();

  #pragma unroll 1
  for (int st=0; st<NSTAGES; ++st){
    if (st < NSTAGES-1){
      char* dst = ldsb + ((st+1)&1)*STAGE_BYTES;
      load_lds_16B(src0, dst + w*1024);
      load_lds_16B(src1, dst + 16384 + w*1024);
      src0 += SADV; src1 += SADV;
    }

    const char* buf = ldsb + (st&1)*STAGE_BYTES;
    #pragma unroll 4
    for (int s=0; s<STAGE_STEPS; ++s){
      const char* psb = buf + s*512;
      f16x4 k4 = *(const f16x4*)(psb + g*8);
      f16x4 q4 = *(const f16x4*)(psb + 256 + g*8);
      f16 vh   = *(const f16*)(psb + 128 + row*2);
      f16 bh   = *(const f16*)(psb + 384 + row*2);

      uint2 ku = __builtin_bit_cast(uint2, k4);
      uint2 qu = __builtin_bit_cast(uint2, q4);
      f16x2 kl = __builtin_bit_cast(f16x2, ku.x), kh = __builtin_bit_cast(f16x2, ku.y);
      f16x2 ql = __builtin_bit_cast(f16x2, qu.x), qh = __builtin_bit_cast(f16x2, qu.y);
      float v  = (float)vh;
      float bb = (float)bh;   // pre-scaled by C2LOG2E

      float r = fdot2(P1, kh, fdot2(P0, kl, 0.f));
      r = dpp_reduce16(r);
      float dl = (v - r) * C2LOG2E;

      f32x2 d2  = { dl, dl };
      f32x2 bb2 = { bb, bb };
      f32x2 k01 = { (float)kl[0], (float)kl[1] };
      f32x2 k23 = { (float)kh[0], (float)kh[1] };
      f32x2 arg01 = bb2*S01 + d2*k01;     // v_pk_fma_f32
      f32x2 arg23 = bb2*S23 + d2*k23;

      f32x2 e01 = { exp2_fast(arg01.x), exp2_fast(arg01.y) };
      f32x2 e23 = { exp2_fast(arg23.x), exp2_fast(arg23.y) };
      f32x2 one2 = { 1.f, 1.f };
      e01 += one2;  e23 += one2;
      f32x2 t01 = { __builtin_amdgcn_rcpf(e01.x), __builtin_amdgcn_rcpf(e01.y) };
      f32x2 t23 = { __builtin_amdgcn_rcpf(e23.x), __builtin_amdgcn_rcpf(e23.y) };
      f32x2 m2 = { -2.f, -2.f };
      S01 = m2*t01 + one2;
      S23 = m2*t23 + one2;
      P0 = pack2(S01.x, S01.y);
      P1 = pack2(S23.x, S23.y);

      float sq = fdot2(P1, qh, fdot2(P0, ql, 0.f));
      sq = dpp_reduce16(sq);
      if (g == 0) outp[(size_t)(st*STAGE_STEPS + s) * (BATCH*512)] = sq;
    }
    __syncthreads();
  }

  // S_final: [B, H, n, n]
  size_t sbase = ((size_t)p*NHEAD + row)*NHEAD + g*4;
  float4 v4 = { S01.x, S01.y, S23.x, S23.y };
  *(float4*)(S_out + sbase) = v4;
}

// ---------------- postpass: out = sq * silu(sq), in place ----------------
__global__ __launch_bounds__(256) void silu_kernel(float4* __restrict__ o, int n4){
  int i = blockIdx.x*blockDim.x + threadIdx.x;
  int stride = gridDim.x*blockDim.x;
  for (; i < n4; i += stride){
    float4 v = o[i];
    v.x = v.x*v.x*sigmoid_fast(v.x);
    v.y = v.y*v.y*sigmoid_fast(v.y);
    v.z = v.z*v.z*sigmoid_fast(v.z);
    v.w = v.w*v.w*sigmoid_fast(v.w);
    o[i] = v;
  }
}

// ---------------- launch ----------------
extern "C" void kernel_launch(void* const* d_in, const int* in_sizes, int n_in,
                              void* d_out, int out_size, void* d_ws, size_t ws_size,
                              hipStream_t stream){
  const float* x  = (const float*)d_in[0];
  const float* Wk = (const float*)d_in[1];
  const float* Wv = (const float*)d_in[2];
  const float* Wq = (const float*)d_in[3];
  const float* Wb = (const float*)d_in[4];
  const float* bb = (const float*)d_in[5];

  float* out = (float*)d_out;
  float* Sf  = out + (size_t)TSTEPS*BATCH*512;

  char* ws = (char*)d_ws;
  f16* Yh = (f16*)ws;                                // 128 MB (row-major T*B x 2048)
  f16* xh = (f16*)(ws + 134217728);                  // 64 MB
  f16* wh = (f16*)(ws + 134217728 + 67108864);       // 4 MB

  cast_kernel<<<2048, 256, 0, stream>>>((const float4*)x, (f16x4*)xh, (MROWS*DIMK)/4);
  cast4_kernel<<<2048, 256, 0, stream>>>((const float4*)Wk, (const float4*)Wv,
                                         (const float4*)Wq, (const float4*)Wb,
                                         (f16x4*)wh);

  dim3 g(MROWS/BM, NPROJ/BN);
  gemm_xwT<<<g, 256, 0, stream>>>(xh, wh, Yh);

  prep_kernel<<<(TSTEPS*BATCH*HEADS)/4, 256, 0, stream>>>(Yh, bb);

  scan_kernel<<<256, 1024, 0, stream>>>(Yh, out, Sf);

  silu_kernel<<<2048, 256, 0, stream>>>((float4*)out, (TSTEPS*BATCH*512)/4);
}